// Round 9
// baseline (2752.940 us; speedup 1.0000x reference)
//
#include <hip/hip_runtime.h>
#include <hip/hip_bf16.h>
#include <cstdint>

#define B_   4
#define P_   8
#define N_   10000
#define C_   64
#define H_   256
#define E_   160000
#define HOR_ 4
#define BN_  (B_ * N_)     // 40000
#define MPAD 40064         // 313 * 128

typedef __bf16 bf16;
typedef __attribute__((ext_vector_type(8))) __bf16 bf16x8;
typedef __attribute__((ext_vector_type(4))) float f32x4;

__device__ __forceinline__ void gl2lds16(const bf16* g, bf16* l) {
    __builtin_amdgcn_global_load_lds(
        (const __attribute__((address_space(1))) void*)g,
        (__attribute__((address_space(3))) void*)l, 16, 0, 0);
}

// ---------------------------------------------------------------- GEMM ----
// C[M,N] = A[M,K] @ Bt[N,K]^T. Round-0 structure (single-buffer,
// 2-barrier): round-1 dbuf experiment cost occupancy and regressed.
template <int BIAS, int RELU, int OUTBF, int PROJ>
__global__ __launch_bounds__(256) void gemm_k(
    const bf16* __restrict__ A, const bf16* __restrict__ Bt,
    void* __restrict__ Cp, const float* __restrict__ bias,
    int K, int Nn, int tstep)
{
    __shared__ __align__(16) bf16 As[128 * 32];
    __shared__ __align__(16) bf16 Bs[128 * 32];

    const int tid  = threadIdx.x;
    const int m0   = blockIdx.y * 128;
    const int n0   = blockIdx.x * 128;
    const int wave = tid >> 6;
    const int lane = tid & 63;
    const int wm   = (wave >> 1) << 6;
    const int wn   = (wave & 1) << 6;
    const int lr   = lane & 15;
    const int kg   = lane >> 4;

    f32x4 acc[4][4] = {};

    const int r0 = tid >> 2;
    const int k0 = (tid & 3) << 3;

    for (int kk = 0; kk < K; kk += 32) {
        const bf16* ga = A  + (size_t)(m0 + r0) * K + kk + k0;
        const bf16* gb = Bt + (size_t)(n0 + r0) * K + kk + k0;
        gl2lds16(ga,                  As + tid * 8);
        gl2lds16(ga + 64 * (size_t)K, As + 2048 + tid * 8);
        gl2lds16(gb,                  Bs + tid * 8);
        gl2lds16(gb + 64 * (size_t)K, Bs + 2048 + tid * 8);
        __syncthreads();

        bf16x8 af[4], bfv[4];
#pragma unroll
        for (int i = 0; i < 4; ++i)
            af[i] = *reinterpret_cast<const bf16x8*>(&As[(wm + i * 16 + lr) * 32 + kg * 8]);
#pragma unroll
        for (int j = 0; j < 4; ++j)
            bfv[j] = *reinterpret_cast<const bf16x8*>(&Bs[(wn + j * 16 + lr) * 32 + kg * 8]);
#pragma unroll
        for (int i = 0; i < 4; ++i)
#pragma unroll
            for (int j = 0; j < 4; ++j)
                acc[i][j] = __builtin_amdgcn_mfma_f32_16x16x32_bf16(af[i], bfv[j], acc[i][j], 0, 0, 0);
        __syncthreads();
    }

#pragma unroll
    for (int i = 0; i < 4; ++i) {
#pragma unroll
        for (int j = 0; j < 4; ++j) {
#pragma unroll
            for (int v = 0; v < 4; ++v) {
                int row = m0 + wm + i * 16 + kg * 4 + v;
                int col = n0 + wn + j * 16 + lr;
                float val = acc[i][j][v];
                if (BIAS) val += bias[col];
                if (RELU) val = fmaxf(val, 0.f);
                if (PROJ) {
                    if (col < C_ && row < BN_) {
                        int b = row / N_, n = row - b * N_;
                        reinterpret_cast<float*>(Cp)[(((size_t)b * HOR_ + tstep) * N_ + n) * C_ + col] = val;
                    }
                } else if (OUTBF) {
                    reinterpret_cast<bf16*>(Cp)[(size_t)row * Nn + col] = (bf16)val;
                } else {
                    reinterpret_cast<float*>(Cp)[(size_t)row * Nn + col] = val;
                }
            }
        }
    }
}

// ----------------------------------------------------------- fused GRU ----
// Round-9 restructure: the kernel was latency-bound at 2 waves/SIMD
// (140 regs = 64 AGPR acc + 76 VGPR; m69 occupancy buckets 64/128/256).
// Scheduling tweaks were exhausted (r1/r6/r8 all <=0). Shrink the
// per-wave tile 64x16 -> 32x16 cols so acc[4][2] = 32 AGPR; main-loop
// VGPR ~60-70 -> total <~100 <= 128 -> __launch_bounds__(256,4) = 4
// waves/SIMD (2x latency hiding). Block = 32 rows x 64 gate-cols
// (4 waves x 16 cols), 1252 strips of 32 rows, LDS 4 KB, staging 1
// gl2lds16/thread/iter. W packing unchanged (cg = cb*4 + wave).
// Proven r5 two-barrier schedule. Known cost: W L2 traffic ~2x (less
// row-reuse per W fragment) — if dur sticks ~50us at high occupancy,
// W-traffic is the binder -> 64-row strips next.
__global__ __launch_bounds__(256, 4) void gru_fused_k(
    const bf16* __restrict__ X, const bf16* __restrict__ Hc,
    bf16* __restrict__ Hn,
    const bf16* __restrict__ Wpk,
    const float* __restrict__ bih, const float* __restrict__ bhh)
{
    // bijective XCD swizzle: the 4 col-blocks of a strip share id%8
    // -> same XCD -> X/H strip L2-local. 157*8 strip slots, 4 pad.
    const int id    = blockIdx.x;
    const int shi   = id >> 5;
    const int cb    = (id >> 3) & 3;           // col-block: 64 gate-cols
    const int slo   = id & 7;
    const int strip = (shi << 3) | slo;
    if (strip >= 1252) return;

    __shared__ __align__(16) bf16 Xs[32 * 32];   // 2 KB
    __shared__ __align__(16) bf16 Hs[32 * 32];   // 2 KB

    const int tid  = threadIdx.x;
    const int m0   = strip * 32;
    const int wave = tid >> 6;
    const int lane = tid & 63;
    const int lr   = lane & 15;
    const int kg   = lane >> 4;

    f32x4 acc[4][2] = {};                  // [gate][i] : 32 AGPRs
                                           // 0=r 1=z 2=in(x) 3=hn(h)

    // staging: tids 0-127 stage X (waves 0,1), 128-255 stage H (2,3);
    // 1 x 16B per thread covers the 4 KB (X+H) 32x32 chunk.
    const int sr = (tid & 127) >> 2;       // row 0..31
    const int sk = (tid & 3) << 3;         // k-elem 0,8,16,24
    const bf16* gsrc = (tid < 128) ? X : Hc;
    bf16* ldst = ((tid < 128) ? Xs : Hs) + (tid & 127) * 8;
    const bf16* grow = gsrc + (size_t)(m0 + sr) * 256 + sk;

    // packed-W per-thread base: [(cg)][kchunk(8)][gate(6)][lane(64)][8]
    const bf16* wb = Wpk + (size_t)(cb * 4 + wave) * 24576 + lane * 8;

    for (int it = 0; it < 8; ++it) {
        gl2lds16(grow + it * 32, ldst);
        const bf16* wit = wb + (size_t)it * 3072;
        bf16x8 w0 = *reinterpret_cast<const bf16x8*>(&wit[0]);
        bf16x8 w1 = *reinterpret_cast<const bf16x8*>(&wit[512]);
        bf16x8 w2 = *reinterpret_cast<const bf16x8*>(&wit[1024]);
        bf16x8 w3 = *reinterpret_cast<const bf16x8*>(&wit[1536]);
        bf16x8 w4 = *reinterpret_cast<const bf16x8*>(&wit[2048]);
        bf16x8 w5 = *reinterpret_cast<const bf16x8*>(&wit[2560]);
        __syncthreads();

        bf16x8 fa[2], fh[2];
#pragma unroll
        for (int i = 0; i < 2; ++i) {
            fa[i] = *reinterpret_cast<const bf16x8*>(&Xs[(i * 16 + lr) * 32 + kg * 8]);
            fh[i] = *reinterpret_cast<const bf16x8*>(&Hs[(i * 16 + lr) * 32 + kg * 8]);
        }
        // phase A: X-side
#pragma unroll
        for (int i = 0; i < 2; ++i)
            acc[0][i] = __builtin_amdgcn_mfma_f32_16x16x32_bf16(fa[i], w0, acc[0][i], 0, 0, 0);
#pragma unroll
        for (int i = 0; i < 2; ++i)
            acc[1][i] = __builtin_amdgcn_mfma_f32_16x16x32_bf16(fa[i], w1, acc[1][i], 0, 0, 0);
#pragma unroll
        for (int i = 0; i < 2; ++i)
            acc[2][i] = __builtin_amdgcn_mfma_f32_16x16x32_bf16(fa[i], w2, acc[2][i], 0, 0, 0);
        // phase B: H-side
#pragma unroll
        for (int i = 0; i < 2; ++i)
            acc[0][i] = __builtin_amdgcn_mfma_f32_16x16x32_bf16(fh[i], w3, acc[0][i], 0, 0, 0);
#pragma unroll
        for (int i = 0; i < 2; ++i)
            acc[1][i] = __builtin_amdgcn_mfma_f32_16x16x32_bf16(fh[i], w4, acc[1][i], 0, 0, 0);
#pragma unroll
        for (int i = 0; i < 2; ++i)
            acc[3][i] = __builtin_amdgcn_mfma_f32_16x16x32_bf16(fh[i], w5, acc[3][i], 0, 0, 0);
        __syncthreads();
    }

    const int col = cb * 64 + wave * 16 + lr;
    const float b_r  = bih[col]       + bhh[col];
    const float b_z  = bih[256 + col] + bhh[256 + col];
    const float bi_n = bih[512 + col];
    const float bh_n = bhh[512 + col];
#pragma unroll
    for (int i = 0; i < 2; ++i) {
#pragma unroll
        for (int v = 0; v < 4; ++v) {
            int row = m0 + i * 16 + kg * 4 + v;
            float r = __fdividef(1.f, 1.f + __expf(-(acc[0][i][v] + b_r)));
            float z = __fdividef(1.f, 1.f + __expf(-(acc[1][i][v] + b_z)));
            float a = (acc[2][i][v] + bi_n) + r * (acc[3][i][v] + bh_n);
            a = fminf(fmaxf(a, -15.f), 15.f);
            float t2 = __expf(2.f * a);
            float nn = __fdividef(t2 - 1.f, t2 + 1.f);
            float hold = (float)Hc[(size_t)row * 256 + col];
            Hn[(size_t)row * 256 + col] = (bf16)((1.f - z) * nn + z * hold);
        }
    }
}

// ------------------------------------------------- conv A-matrix build ----
struct __attribute__((aligned(8))) bf4 { bf16 b[4]; };

__global__ __launch_bounds__(256) void gather_conv_k(
    const float* __restrict__ xbase, long long sB, long long sN,
    const int* __restrict__ rp0, const int* __restrict__ col0,
    const int* __restrict__ rp1, const int* __restrict__ col1,
    bf16* __restrict__ Aconv)
{
    int wid  = (blockIdx.x * 256 + threadIdx.x) >> 6;
    int lane = threadIdx.x & 63;
    if (wid >= BN_) return;
    int b = wid / N_;
    int n = wid - b * N_;
    int eg = lane >> 4;
    int cl = lane & 15;
    const float* xb = xbase + (size_t)b * sB;

    float4 xv = *reinterpret_cast<const float4*>(&xb[(size_t)n * sN + cl * 4]);

    float4 s0 = {0.f, 0.f, 0.f, 0.f};
    int st = rp0[n], en = rp0[n + 1];
    float d0 = fmaxf((float)(en - st), 1.f);
    for (int e = st + eg; e < en; e += 4) {
        const float4 v = *reinterpret_cast<const float4*>(&xb[(size_t)col0[e] * sN + cl * 4]);
        s0.x += v.x; s0.y += v.y; s0.z += v.z; s0.w += v.w;
    }

    float4 s1 = {0.f, 0.f, 0.f, 0.f};
    st = rp1[n]; en = rp1[n + 1];
    float d1 = fmaxf((float)(en - st), 1.f);
    for (int e = st + eg; e < en; e += 4) {
        const float4 v = *reinterpret_cast<const float4*>(&xb[(size_t)col1[e] * sN + cl * 4]);
        s1.x += v.x; s1.y += v.y; s1.z += v.z; s1.w += v.w;
    }

#pragma unroll
    for (int m = 16; m <= 32; m <<= 1) {
        s0.x += __shfl_xor(s0.x, m, 64); s0.y += __shfl_xor(s0.y, m, 64);
        s0.z += __shfl_xor(s0.z, m, 64); s0.w += __shfl_xor(s0.w, m, 64);
        s1.x += __shfl_xor(s1.x, m, 64); s1.y += __shfl_xor(s1.y, m, 64);
        s1.z += __shfl_xor(s1.z, m, 64); s1.w += __shfl_xor(s1.w, m, 64);
    }

    if (eg == 0) {
        float r0 = 1.f / d0, r1 = 1.f / d1;
        bf16* row = Aconv + (size_t)wid * 192;
        bf4 o;
        o.b[0] = (bf16)(s0.x * r0); o.b[1] = (bf16)(s0.y * r0);
        o.b[2] = (bf16)(s0.z * r0); o.b[3] = (bf16)(s0.w * r0);
        *reinterpret_cast<bf4*>(&row[cl * 4]) = o;
        o.b[0] = (bf16)xv.x; o.b[1] = (bf16)xv.y; o.b[2] = (bf16)xv.z; o.b[3] = (bf16)xv.w;
        *reinterpret_cast<bf4*>(&row[64 + cl * 4]) = o;
        o.b[0] = (bf16)(s1.x * r1); o.b[1] = (bf16)(s1.y * r1);
        o.b[2] = (bf16)(s1.z * r1); o.b[3] = (bf16)(s1.w * r1);
        *reinterpret_cast<bf4*>(&row[128 + cl * 4]) = o;
    }
}

// ------------------------------------------------------------ CSR build ----
__global__ void count_k(const int* __restrict__ ei, int* __restrict__ cnt) {
    int e = blockIdx.x * 256 + threadIdx.x;
    if (e < E_) atomicAdd(&cnt[ei[E_ + e]], 1);
}

__global__ __launch_bounds__(1024) void scan_k(
    const int* __restrict__ cnt, int* __restrict__ rp, int* __restrict__ fill)
{
    __shared__ int sums[1024];
    int t = threadIdx.x;
    const int chunk = 10;
    int lo = t * chunk;
    int hi = lo + chunk; if (hi > N_) hi = N_;
    int s = 0;
    for (int i = lo; i < hi; ++i) s += cnt[i];
    sums[t] = s;
    __syncthreads();
    for (int off = 1; off < 1024; off <<= 1) {
        int u = (t >= off) ? sums[t - off] : 0;
        __syncthreads();
        sums[t] += u;
        __syncthreads();
    }
    int base = (t == 0) ? 0 : sums[t - 1];
    for (int i = lo; i < hi; ++i) { rp[i] = base; fill[i] = base; base += cnt[i]; }
    if (t == 1023) rp[N_] = sums[1023];
}

__global__ void fill_k(const int* __restrict__ ei, int* __restrict__ fill,
                       int* __restrict__ colarr) {
    int e = blockIdx.x * 256 + threadIdx.x;
    if (e < E_) {
        int p = atomicAdd(&fill[ei[E_ + e]], 1);
        colarr[p] = ei[e];
    }
}

// --------------------------------------------------------- weight prep ----
// Pack GRU weights fragment-major so a wave's MFMA B-fragment is one
// contiguous 1024B line: out[cg][kc][g][lane][e] =
// W6[g][cg*16+(lane&15)][kc*32+(lane>>4)*8+e], W6 = Wih(g<3)/Whh.
__global__ void pack_w_k(const float* __restrict__ Wih, const float* __restrict__ Whh,
                         bf16* __restrict__ out) {
    int idx = blockIdx.x * 256 + threadIdx.x;
    if (idx >= 6 * 256 * 256) return;
    int e    = idx & 7;
    int lane = (idx >> 3) & 63;
    int rest = idx >> 9;
    int g    = rest % 6;
    int kc   = (rest / 6) & 7;
    int wj   = rest / 48;             // cg in [0,16)
    int row  = (wj >> 1) * 32 + (wj & 1) * 16 + (lane & 15);
    int k    = kc * 32 + (lane >> 4) * 8 + e;
    float v  = (g < 3) ? Wih[(g * 256 + row) * 256 + k]
                       : Whh[((g - 3) * 256 + row) * 256 + k];
    out[idx] = (bf16)v;
}

__global__ void build_conv_bt_k(const float* __restrict__ Wl0, const float* __restrict__ Wr0,
                                const float* __restrict__ Wl1, const float* __restrict__ Wr1,
                                bf16* __restrict__ Bt) {
    int idx = blockIdx.x * 256 + threadIdx.x;
    if (idx >= 256 * 192) return;
    int n = idx / 192, k = idx - n * 192;
    float v;
    if (k < 64)       v = Wl0[k * 256 + n];
    else if (k < 128) v = Wr0[(k - 64) * 256 + n] + Wr1[(k - 64) * 256 + n];
    else              v = Wl1[(k - 128) * 256 + n];
    Bt[idx] = (bf16)v;
}

__global__ void build_conv_bias_k(const float* __restrict__ bl0, const float* __restrict__ bl1,
                                  float* __restrict__ bias) {
    int i = threadIdx.x;
    if (i < 256) bias[i] = bl0[i] + bl1[i];
}

__global__ void build_proj_k(const float* __restrict__ Wp, const float* __restrict__ bp,
                             bf16* __restrict__ Bt, float* __restrict__ bias) {
    int idx = blockIdx.x * 256 + threadIdx.x;
    if (idx < 128 * 256) {
        int n = idx >> 8, k = idx & 255;
        Bt[idx] = (bf16)(n < 64 ? Wp[n * 256 + k] : 0.f);
    }
    if (idx < 128) bias[idx] = (idx < 64) ? bp[idx] : 0.f;
}

// ---------------------------------------------------------------- host ----
extern "C" void kernel_launch(void* const* d_in, const int* in_sizes, int n_in,
                              void* d_out, int out_size, void* d_ws, size_t ws_size,
                              hipStream_t stream)
{
    const float* x_seq = (const float*)d_in[0];
    const int*   ei0   = (const int*)d_in[1];
    const int*   ei1   = (const int*)d_in[2];
    const float* Wl0   = (const float*)d_in[3];
    const float* bl0   = (const float*)d_in[4];
    const float* Wr0   = (const float*)d_in[5];
    const float* Wl1   = (const float*)d_in[6];
    const float* bl1   = (const float*)d_in[7];
    const float* Wr1   = (const float*)d_in[8];
    const float* Wp    = (const float*)d_in[9];
    const float* bp    = (const float*)d_in[10];
    const float* gWih[3], *gWhh[3], *gbih[3], *gbhh[3];
    for (int g = 0; g < 3; ++g) {
        gWih[g] = (const float*)d_in[11 + 4 * g];
        gWhh[g] = (const float*)d_in[12 + 4 * g];
        gbih[g] = (const float*)d_in[13 + 4 * g];
        gbhh[g] = (const float*)d_in[14 + 4 * g];
    }

    char* p = (char*)d_ws;
    auto alloc = [&](size_t bytes) -> char* {
        char* r = p; p += (bytes + 255) & ~(size_t)255; return r;
    };
    bf16*  Aconv  = (bf16*)alloc((size_t)MPAD * 192 * 2);
    bf16*  cbuf   = (bf16*)alloc((size_t)MPAD * 256 * 2);
    bf16*  hbuf[6];
    for (int g = 0; g < 6; ++g) hbuf[g] = (bf16*)alloc((size_t)MPAD * 256 * 2);
    bf16*  wpk[3];
    for (int g = 0; g < 3; ++g)
        wpk[g] = (bf16*)alloc((size_t)6 * 256 * 256 * 2);
    bf16*  btconv = (bf16*)alloc((size_t)256 * 192 * 2);
    float* bconv  = (float*)alloc(256 * 4);
    bf16*  btproj = (bf16*)alloc((size_t)128 * 256 * 2);
    float* bproj  = (float*)alloc(128 * 4);
    int* cnt0  = (int*)alloc(N_ * 4);
    int* cnt1  = (int*)alloc(N_ * 4);
    int* rp0   = (int*)alloc((N_ + 1) * 4);
    int* rp1   = (int*)alloc((N_ + 1) * 4);
    int* fill0 = (int*)alloc((N_ + 1) * 4);
    int* fill1 = (int*)alloc((N_ + 1) * 4);
    int* col0  = (int*)alloc(E_ * 4);
    int* col1  = (int*)alloc(E_ * 4);

    // h cur buffers (0,1,2) must start at zero; nxt (3,4,5) fully written.
    hipMemsetAsync(Aconv, 0, (size_t)MPAD * 192 * 2, stream);
    for (int g = 0; g < 3; ++g)
        hipMemsetAsync(hbuf[g], 0, (size_t)MPAD * 256 * 2, stream);
    hipMemsetAsync(cnt0, 0, N_ * 4, stream);
    hipMemsetAsync(cnt1, 0, N_ * 4, stream);

    for (int g = 0; g < 3; ++g)
        pack_w_k<<<1536, 256, 0, stream>>>(gWih[g], gWhh[g], wpk[g]);
    build_conv_bt_k<<<192, 256, 0, stream>>>(Wl0, Wr0, Wl1, Wr1, btconv);
    build_conv_bias_k<<<1, 256, 0, stream>>>(bl0, bl1, bconv);
    build_proj_k<<<128, 256, 0, stream>>>(Wp, bp, btproj, bproj);

    count_k<<<(E_ + 255) / 256, 256, 0, stream>>>(ei0, cnt0);
    count_k<<<(E_ + 255) / 256, 256, 0, stream>>>(ei1, cnt1);
    scan_k<<<1, 1024, 0, stream>>>(cnt0, rp0, fill0);
    scan_k<<<1, 1024, 0, stream>>>(cnt1, rp1, fill1);
    fill_k<<<(E_ + 255) / 256, 256, 0, stream>>>(ei0, fill0, col0);
    fill_k<<<(E_ + 255) / 256, 256, 0, stream>>>(ei1, fill1, col1);

    bf16 *hc[3] = { hbuf[0], hbuf[1], hbuf[2] };
    bf16 *hn[3] = { hbuf[3], hbuf[4], hbuf[5] };

    auto do_conv = [&](const float* xb, long long sB, long long sN) {
        gather_conv_k<<<10000, 256, 0, stream>>>(xb, sB, sN, rp0, col0, rp1, col1, Aconv);
        gemm_k<1, 1, 1, 0><<<dim3(2, 313, 1), 256, 0, stream>>>(
            Aconv, btconv, cbuf, bconv, 192, 256, 0);
    };
    // 157 strip-groups x 4 col-blocks x 8 strip-low = 5024 blocks (16 exit)
    auto do_grus = [&]() {
        gru_fused_k<<<5024, 256, 0, stream>>>(
            cbuf, hc[0], hn[0], wpk[0], gbih[0], gbhh[0]);
        gru_fused_k<<<5024, 256, 0, stream>>>(
            hn[0], hc[1], hn[1], wpk[1], gbih[1], gbhh[1]);
        gru_fused_k<<<5024, 256, 0, stream>>>(
            hn[1], hc[2], hn[2], wpk[2], gbih[2], gbhh[2]);
        for (int g = 0; g < 3; ++g) { bf16* t = hc[g]; hc[g] = hn[g]; hn[g] = t; }
    };

    // encoder
    for (int ps = 0; ps < P_; ++ps) {
        do_conv(x_seq + (size_t)ps * N_ * C_, (long long)P_ * N_ * C_, C_);
        do_grus();
    }

    // decoder: t=0 reuses encoder step-7 conv output (same x input)
    float* out = (float*)d_out;
    for (int t = 0; t < HOR_; ++t) {
        if (t > 0)
            do_conv(out + (size_t)(t - 1) * N_ * C_, (long long)HOR_ * N_ * C_, C_);
        do_grus();
        gemm_k<1, 0, 0, 1><<<dim3(1, 313, 1), 256, 0, stream>>>(
            hc[2], btproj, out, bproj, 256, 128, t);
    }
}

// Round 10
// 2651.424 us; speedup vs baseline: 1.0383x; 1.0383x over previous
//
#include <hip/hip_runtime.h>
#include <hip/hip_bf16.h>
#include <cstdint>

#define B_   4
#define P_   8
#define N_   10000
#define C_   64
#define H_   256
#define E_   160000
#define HOR_ 4
#define BN_  (B_ * N_)     // 40000
#define MPAD 40064         // 313 * 128

typedef __bf16 bf16;
typedef __attribute__((ext_vector_type(8))) __bf16 bf16x8;
typedef __attribute__((ext_vector_type(4))) float f32x4;

__device__ __forceinline__ void gl2lds16(const bf16* g, bf16* l) {
    __builtin_amdgcn_global_load_lds(
        (const __attribute__((address_space(1))) void*)g,
        (__attribute__((address_space(3))) void*)l, 16, 0, 0);
}

// ---------------------------------------------------------------- GEMM ----
// C[M,N] = A[M,K] @ Bt[N,K]^T. Round-0 proven structure (single-buffer,
// 2-barrier). Round-10: optional batch dim via blockIdx.z with element
// strides aZ (A) / cZ (C) so the 8 encoder conv GEMMs run as one launch.
template <int BIAS, int RELU, int OUTBF, int PROJ>
__global__ __launch_bounds__(256) void gemm_k(
    const bf16* __restrict__ A, const bf16* __restrict__ Bt,
    void* __restrict__ Cp, const float* __restrict__ bias,
    int K, int Nn, int tstep, size_t aZ, size_t cZ)
{
    __shared__ __align__(16) bf16 As[128 * 32];
    __shared__ __align__(16) bf16 Bs[128 * 32];

    const int tid  = threadIdx.x;
    const int m0   = blockIdx.y * 128;
    const int n0   = blockIdx.x * 128;
    const int wave = tid >> 6;
    const int lane = tid & 63;
    const int wm   = (wave >> 1) << 6;
    const int wn   = (wave & 1) << 6;
    const int lr   = lane & 15;
    const int kg   = lane >> 4;

    const bf16* Az = A + (size_t)blockIdx.z * aZ;
    const size_t cBase = (size_t)blockIdx.z * cZ;

    f32x4 acc[4][4] = {};

    const int r0 = tid >> 2;
    const int k0 = (tid & 3) << 3;

    for (int kk = 0; kk < K; kk += 32) {
        const bf16* ga = Az + (size_t)(m0 + r0) * K + kk + k0;
        const bf16* gb = Bt + (size_t)(n0 + r0) * K + kk + k0;
        gl2lds16(ga,                  As + tid * 8);
        gl2lds16(ga + 64 * (size_t)K, As + 2048 + tid * 8);
        gl2lds16(gb,                  Bs + tid * 8);
        gl2lds16(gb + 64 * (size_t)K, Bs + 2048 + tid * 8);
        __syncthreads();

        bf16x8 af[4], bfv[4];
#pragma unroll
        for (int i = 0; i < 4; ++i)
            af[i] = *reinterpret_cast<const bf16x8*>(&As[(wm + i * 16 + lr) * 32 + kg * 8]);
#pragma unroll
        for (int j = 0; j < 4; ++j)
            bfv[j] = *reinterpret_cast<const bf16x8*>(&Bs[(wn + j * 16 + lr) * 32 + kg * 8]);
#pragma unroll
        for (int i = 0; i < 4; ++i)
#pragma unroll
            for (int j = 0; j < 4; ++j)
                acc[i][j] = __builtin_amdgcn_mfma_f32_16x16x32_bf16(af[i], bfv[j], acc[i][j], 0, 0, 0);
        __syncthreads();
    }

#pragma unroll
    for (int i = 0; i < 4; ++i) {
#pragma unroll
        for (int j = 0; j < 4; ++j) {
#pragma unroll
            for (int v = 0; v < 4; ++v) {
                int row = m0 + wm + i * 16 + kg * 4 + v;
                int col = n0 + wn + j * 16 + lr;
                float val = acc[i][j][v];
                if (BIAS) val += bias[col];
                if (RELU) val = fmaxf(val, 0.f);
                if (PROJ) {
                    if (col < C_ && row < BN_) {
                        int b = row / N_, n = row - b * N_;
                        reinterpret_cast<float*>(Cp)[(((size_t)b * HOR_ + tstep) * N_ + n) * C_ + col] = val;
                    }
                } else if (OUTBF) {
                    reinterpret_cast<bf16*>(Cp)[cBase + (size_t)row * Nn + col] = (bf16)val;
                } else {
                    reinterpret_cast<float*>(Cp)[cBase + (size_t)row * Nn + col] = val;
                }
            }
        }
    }
}

// ----------------------------------------------------------- fused GRU ----
// EXACT round-5 config (session best): 128 rows x 32 gate-cols per block,
// XCD-aware swizzle, fused r/z acc (acc[4][4] = 64 AGPR), phase-split
// compute, W pre-packed fragment-major and loaded global->VGPR.
// Post-r9 diagnosis: kernel sits at the per-CU operand-delivery wall
// (~8KB/wave-iter LDS-read @ ~85 B/cyc + 6KB L1 W @ ~64 B/cyc vs 116
// matrix-cyc of MFMA -> ~25% MfmaUtil cap; measured 22-23%). Occupancy
// (r9 2x: null), scheduling (r1/r6/r8: null/neg) don't move it; (4,1)
// fragment geometry is bytes/MFMA-optimal under 64 AGPR.
__global__ __launch_bounds__(256, 2) void gru_fused_k(
    const bf16* __restrict__ X, const bf16* __restrict__ Hc,
    bf16* __restrict__ Hn,
    const bf16* __restrict__ Wpk,
    const float* __restrict__ bih, const float* __restrict__ bhh)
{
    const int id    = blockIdx.x;
    const int sblk  = id >> 6;
    const int jblk  = (id >> 3) & 7;
    const int slow  = id & 7;
    const int strip = (sblk << 3) | slow;
    if (strip >= 313) return;

    __shared__ __align__(16) bf16 Xs[128 * 32];
    __shared__ __align__(16) bf16 Hs[128 * 32];

    const int tid  = threadIdx.x;
    const int m0   = strip * 128;
    const int j0   = jblk * 32;            // gate-col base (0..224)
    const int wave = tid >> 6;
    const int lane = tid & 63;
    const int wm   = (wave >> 1) << 6;     // 0 / 64
    const int wn   = (wave & 1) << 4;      // 0 / 16
    const int wv   = wave & 1;
    const int lr   = lane & 15;
    const int kg   = lane >> 4;

    f32x4 acc[4][4] = {};                  // [gate][i] : 64 AGPRs
                                           // 0=r 1=z 2=in(x) 3=hn(h)

    const int r0 = tid >> 2;
    const int k0 = (tid & 3) << 3;

    // packed-W per-thread base: fragment layout
    // [(jblk*2+wv)][it(8)][gate(6)][lane(64)][8 bf16]
    const bf16* wb = Wpk + (size_t)(jblk * 2 + wv) * 24576 + lane * 8;

    for (int it = 0; it < 8; ++it) {
        const int kk = it * 32;
        gl2lds16(X  + (size_t)(m0 + r0) * 256 + kk + k0,      Xs + tid * 8);
        gl2lds16(X  + (size_t)(m0 + r0 + 64) * 256 + kk + k0, Xs + 2048 + tid * 8);
        gl2lds16(Hc + (size_t)(m0 + r0) * 256 + kk + k0,      Hs + tid * 8);
        gl2lds16(Hc + (size_t)(m0 + r0 + 64) * 256 + kk + k0, Hs + 2048 + tid * 8);
        const bf16* wit = wb + it * 3072;
        bf16x8 w0 = *reinterpret_cast<const bf16x8*>(&wit[0]);
        bf16x8 w1 = *reinterpret_cast<const bf16x8*>(&wit[512]);
        bf16x8 w2 = *reinterpret_cast<const bf16x8*>(&wit[1024]);
        bf16x8 w3 = *reinterpret_cast<const bf16x8*>(&wit[1536]);
        bf16x8 w4 = *reinterpret_cast<const bf16x8*>(&wit[2048]);
        bf16x8 w5 = *reinterpret_cast<const bf16x8*>(&wit[2560]);
        __syncthreads();

        // phase A: X-side
        {
            bf16x8 fa[4];
#pragma unroll
            for (int i = 0; i < 4; ++i)
                fa[i] = *reinterpret_cast<const bf16x8*>(&Xs[(wm + i * 16 + lr) * 32 + kg * 8]);
#pragma unroll
            for (int i = 0; i < 4; ++i)
                acc[0][i] = __builtin_amdgcn_mfma_f32_16x16x32_bf16(fa[i], w0, acc[0][i], 0, 0, 0);
#pragma unroll
            for (int i = 0; i < 4; ++i)
                acc[1][i] = __builtin_amdgcn_mfma_f32_16x16x32_bf16(fa[i], w1, acc[1][i], 0, 0, 0);
#pragma unroll
            for (int i = 0; i < 4; ++i)
                acc[2][i] = __builtin_amdgcn_mfma_f32_16x16x32_bf16(fa[i], w2, acc[2][i], 0, 0, 0);
        }
        // phase B: H-side
        {
            bf16x8 fh[4];
#pragma unroll
            for (int i = 0; i < 4; ++i)
                fh[i] = *reinterpret_cast<const bf16x8*>(&Hs[(wm + i * 16 + lr) * 32 + kg * 8]);
#pragma unroll
            for (int i = 0; i < 4; ++i)
                acc[0][i] = __builtin_amdgcn_mfma_f32_16x16x32_bf16(fh[i], w3, acc[0][i], 0, 0, 0);
#pragma unroll
            for (int i = 0; i < 4; ++i)
                acc[1][i] = __builtin_amdgcn_mfma_f32_16x16x32_bf16(fh[i], w4, acc[1][i], 0, 0, 0);
#pragma unroll
            for (int i = 0; i < 4; ++i)
                acc[3][i] = __builtin_amdgcn_mfma_f32_16x16x32_bf16(fh[i], w5, acc[3][i], 0, 0, 0);
        }
        __syncthreads();
    }

    const int col = j0 + wn + lr;
    const float b_r  = bih[col]       + bhh[col];
    const float b_z  = bih[256 + col] + bhh[256 + col];
    const float bi_n = bih[512 + col];
    const float bh_n = bhh[512 + col];
#pragma unroll
    for (int i = 0; i < 4; ++i) {
#pragma unroll
        for (int v = 0; v < 4; ++v) {
            int row = m0 + wm + i * 16 + kg * 4 + v;
            float r = __fdividef(1.f, 1.f + __expf(-(acc[0][i][v] + b_r)));
            float z = __fdividef(1.f, 1.f + __expf(-(acc[1][i][v] + b_z)));
            float a = (acc[2][i][v] + bi_n) + r * (acc[3][i][v] + bh_n);
            a = fminf(fmaxf(a, -15.f), 15.f);
            float t2 = __expf(2.f * a);
            float nn = __fdividef(t2 - 1.f, t2 + 1.f);
            float hold = (float)Hc[(size_t)row * 256 + col];
            Hn[(size_t)row * 256 + col] = (bf16)((1.f - z) * nn + z * hold);
        }
    }
}

// ------------------------------------------------- conv A-matrix build ----
// Round-10: batched over steps via blockIdx.y (sStep = per-step element
// offset into x; Aconv advances MPAD*192 per step).
struct __attribute__((aligned(8))) bf4 { bf16 b[4]; };

__global__ __launch_bounds__(256) void gather_conv_k(
    const float* __restrict__ xbase, long long sB, long long sN, long long sStep,
    const int* __restrict__ rp0, const int* __restrict__ col0,
    const int* __restrict__ rp1, const int* __restrict__ col1,
    bf16* __restrict__ Aconv)
{
    int wid  = (blockIdx.x * 256 + threadIdx.x) >> 6;
    int lane = threadIdx.x & 63;
    if (wid >= BN_) return;
    int b = wid / N_;
    int n = wid - b * N_;
    int eg = lane >> 4;
    int cl = lane & 15;
    const float* xb = xbase + (size_t)blockIdx.y * sStep + (size_t)b * sB;
    bf16* Ac = Aconv + (size_t)blockIdx.y * MPAD * 192;

    float4 xv = *reinterpret_cast<const float4*>(&xb[(size_t)n * sN + cl * 4]);

    float4 s0 = {0.f, 0.f, 0.f, 0.f};
    int st = rp0[n], en = rp0[n + 1];
    float d0 = fmaxf((float)(en - st), 1.f);
    for (int e = st + eg; e < en; e += 4) {
        const float4 v = *reinterpret_cast<const float4*>(&xb[(size_t)col0[e] * sN + cl * 4]);
        s0.x += v.x; s0.y += v.y; s0.z += v.z; s0.w += v.w;
    }

    float4 s1 = {0.f, 0.f, 0.f, 0.f};
    st = rp1[n]; en = rp1[n + 1];
    float d1 = fmaxf((float)(en - st), 1.f);
    for (int e = st + eg; e < en; e += 4) {
        const float4 v = *reinterpret_cast<const float4*>(&xb[(size_t)col1[e] * sN + cl * 4]);
        s1.x += v.x; s1.y += v.y; s1.z += v.z; s1.w += v.w;
    }

#pragma unroll
    for (int m = 16; m <= 32; m <<= 1) {
        s0.x += __shfl_xor(s0.x, m, 64); s0.y += __shfl_xor(s0.y, m, 64);
        s0.z += __shfl_xor(s0.z, m, 64); s0.w += __shfl_xor(s0.w, m, 64);
        s1.x += __shfl_xor(s1.x, m, 64); s1.y += __shfl_xor(s1.y, m, 64);
        s1.z += __shfl_xor(s1.z, m, 64); s1.w += __shfl_xor(s1.w, m, 64);
    }

    if (eg == 0) {
        float r0 = 1.f / d0, r1 = 1.f / d1;
        bf16* row = Ac + (size_t)wid * 192;
        bf4 o;
        o.b[0] = (bf16)(s0.x * r0); o.b[1] = (bf16)(s0.y * r0);
        o.b[2] = (bf16)(s0.z * r0); o.b[3] = (bf16)(s0.w * r0);
        *reinterpret_cast<bf4*>(&row[cl * 4]) = o;
        o.b[0] = (bf16)xv.x; o.b[1] = (bf16)xv.y; o.b[2] = (bf16)xv.z; o.b[3] = (bf16)xv.w;
        *reinterpret_cast<bf4*>(&row[64 + cl * 4]) = o;
        o.b[0] = (bf16)(s1.x * r1); o.b[1] = (bf16)(s1.y * r1);
        o.b[2] = (bf16)(s1.z * r1); o.b[3] = (bf16)(s1.w * r1);
        *reinterpret_cast<bf4*>(&row[128 + cl * 4]) = o;
    }
}

// ------------------------------------------------------------ CSR build ----
__global__ void count_k(const int* __restrict__ ei, int* __restrict__ cnt) {
    int e = blockIdx.x * 256 + threadIdx.x;
    if (e < E_) atomicAdd(&cnt[ei[E_ + e]], 1);
}

__global__ __launch_bounds__(1024) void scan_k(
    const int* __restrict__ cnt, int* __restrict__ rp, int* __restrict__ fill)
{
    __shared__ int sums[1024];
    int t = threadIdx.x;
    const int chunk = 10;
    int lo = t * chunk;
    int hi = lo + chunk; if (hi > N_) hi = N_;
    int s = 0;
    for (int i = lo; i < hi; ++i) s += cnt[i];
    sums[t] = s;
    __syncthreads();
    for (int off = 1; off < 1024; off <<= 1) {
        int u = (t >= off) ? sums[t - off] : 0;
        __syncthreads();
        sums[t] += u;
        __syncthreads();
    }
    int base = (t == 0) ? 0 : sums[t - 1];
    for (int i = lo; i < hi; ++i) { rp[i] = base; fill[i] = base; base += cnt[i]; }
    if (t == 1023) rp[N_] = sums[1023];
}

__global__ void fill_k(const int* __restrict__ ei, int* __restrict__ fill,
                       int* __restrict__ colarr) {
    int e = blockIdx.x * 256 + threadIdx.x;
    if (e < E_) {
        int p = atomicAdd(&fill[ei[E_ + e]], 1);
        colarr[p] = ei[e];
    }
}

// --------------------------------------------------------- weight prep ----
// Pack GRU weights fragment-major so a wave's MFMA B-fragment is one
// contiguous 1024B line: out[(jb*2+wv)][it][g][lane][e] =
// W6[g][jb*32+wv*16+(lane&15)][it*32+(lane>>4)*8+e], W6 = Wih(g<3)/Whh.
__global__ void pack_w_k(const float* __restrict__ Wih, const float* __restrict__ Whh,
                         bf16* __restrict__ out) {
    int idx = blockIdx.x * 256 + threadIdx.x;
    if (idx >= 6 * 256 * 256) return;
    int e    = idx & 7;
    int lane = (idx >> 3) & 63;
    int rest = idx >> 9;
    int g    = rest % 6;
    int it   = (rest / 6) & 7;
    int wj   = rest / 48;             // jb*2 + wv
    int row  = (wj >> 1) * 32 + (wj & 1) * 16 + (lane & 15);
    int k    = it * 32 + (lane >> 4) * 8 + e;
    float v  = (g < 3) ? Wih[(g * 256 + row) * 256 + k]
                       : Whh[((g - 3) * 256 + row) * 256 + k];
    out[idx] = (bf16)v;
}

__global__ void build_conv_bt_k(const float* __restrict__ Wl0, const float* __restrict__ Wr0,
                                const float* __restrict__ Wl1, const float* __restrict__ Wr1,
                                bf16* __restrict__ Bt) {
    int idx = blockIdx.x * 256 + threadIdx.x;
    if (idx >= 256 * 192) return;
    int n = idx / 192, k = idx - n * 192;
    float v;
    if (k < 64)       v = Wl0[k * 256 + n];
    else if (k < 128) v = Wr0[(k - 64) * 256 + n] + Wr1[(k - 64) * 256 + n];
    else              v = Wl1[(k - 128) * 256 + n];
    Bt[idx] = (bf16)v;
}

__global__ void build_conv_bias_k(const float* __restrict__ bl0, const float* __restrict__ bl1,
                                  float* __restrict__ bias) {
    int i = threadIdx.x;
    if (i < 256) bias[i] = bl0[i] + bl1[i];
}

__global__ void build_proj_k(const float* __restrict__ Wp, const float* __restrict__ bp,
                             bf16* __restrict__ Bt, float* __restrict__ bias) {
    int idx = blockIdx.x * 256 + threadIdx.x;
    if (idx < 128 * 256) {
        int n = idx >> 8, k = idx & 255;
        Bt[idx] = (bf16)(n < 64 ? Wp[n * 256 + k] : 0.f);
    }
    if (idx < 128) bias[idx] = (idx < 64) ? bp[idx] : 0.f;
}

// ---------------------------------------------------------------- host ----
extern "C" void kernel_launch(void* const* d_in, const int* in_sizes, int n_in,
                              void* d_out, int out_size, void* d_ws, size_t ws_size,
                              hipStream_t stream)
{
    const float* x_seq = (const float*)d_in[0];
    const int*   ei0   = (const int*)d_in[1];
    const int*   ei1   = (const int*)d_in[2];
    const float* Wl0   = (const float*)d_in[3];
    const float* bl0   = (const float*)d_in[4];
    const float* Wr0   = (const float*)d_in[5];
    const float* Wl1   = (const float*)d_in[6];
    const float* bl1   = (const float*)d_in[7];
    const float* Wr1   = (const float*)d_in[8];
    const float* Wp    = (const float*)d_in[9];
    const float* bp    = (const float*)d_in[10];
    const float* gWih[3], *gWhh[3], *gbih[3], *gbhh[3];
    for (int g = 0; g < 3; ++g) {
        gWih[g] = (const float*)d_in[11 + 4 * g];
        gWhh[g] = (const float*)d_in[12 + 4 * g];
        gbih[g] = (const float*)d_in[13 + 4 * g];
        gbhh[g] = (const float*)d_in[14 + 4 * g];
    }

    // Batched-encoder layout needs ~415 MB; guard on ws_size and fall
    // back to the single-step (round-5) layout otherwise.
    const int big = ws_size >= (size_t)440 * 1024 * 1024;
    const int aSteps = big ? P_ : 1;

    char* p = (char*)d_ws;
    auto alloc = [&](size_t bytes) -> char* {
        char* r = p; p += (bytes + 255) & ~(size_t)255; return r;
    };
    bf16*  Aconv  = (bf16*)alloc((size_t)aSteps * MPAD * 192 * 2);
    bf16*  cbuf   = (bf16*)alloc((size_t)aSteps * MPAD * 256 * 2);
    bf16*  hbuf[6];
    for (int g = 0; g < 6; ++g) hbuf[g] = (bf16*)alloc((size_t)MPAD * 256 * 2);
    bf16*  wpk[3];
    for (int g = 0; g < 3; ++g)
        wpk[g] = (bf16*)alloc((size_t)6 * 256 * 256 * 2);
    bf16*  btconv = (bf16*)alloc((size_t)256 * 192 * 2);
    float* bconv  = (float*)alloc(256 * 4);
    bf16*  btproj = (bf16*)alloc((size_t)128 * 256 * 2);
    float* bproj  = (float*)alloc(128 * 4);
    int* cnt0  = (int*)alloc(N_ * 4);
    int* cnt1  = (int*)alloc(N_ * 4);
    int* rp0   = (int*)alloc((N_ + 1) * 4);
    int* rp1   = (int*)alloc((N_ + 1) * 4);
    int* fill0 = (int*)alloc((N_ + 1) * 4);
    int* fill1 = (int*)alloc((N_ + 1) * 4);
    int* col0  = (int*)alloc(E_ * 4);
    int* col1  = (int*)alloc(E_ * 4);

    // h cur buffers (0,1,2) must start at zero; nxt (3,4,5) fully written.
    // Aconv padding rows (40000..40063 of every slice) must be deterministic.
    hipMemsetAsync(Aconv, 0, (size_t)aSteps * MPAD * 192 * 2, stream);
    for (int g = 0; g < 3; ++g)
        hipMemsetAsync(hbuf[g], 0, (size_t)MPAD * 256 * 2, stream);
    hipMemsetAsync(cnt0, 0, N_ * 4, stream);
    hipMemsetAsync(cnt1, 0, N_ * 4, stream);

    for (int g = 0; g < 3; ++g)
        pack_w_k<<<1536, 256, 0, stream>>>(gWih[g], gWhh[g], wpk[g]);
    build_conv_bt_k<<<192, 256, 0, stream>>>(Wl0, Wr0, Wl1, Wr1, btconv);
    build_conv_bias_k<<<1, 256, 0, stream>>>(bl0, bl1, bconv);
    build_proj_k<<<128, 256, 0, stream>>>(Wp, bp, btproj, bproj);

    count_k<<<(E_ + 255) / 256, 256, 0, stream>>>(ei0, cnt0);
    count_k<<<(E_ + 255) / 256, 256, 0, stream>>>(ei1, cnt1);
    scan_k<<<1, 1024, 0, stream>>>(cnt0, rp0, fill0);
    scan_k<<<1, 1024, 0, stream>>>(cnt1, rp1, fill1);
    fill_k<<<(E_ + 255) / 256, 256, 0, stream>>>(ei0, fill0, col0);
    fill_k<<<(E_ + 255) / 256, 256, 0, stream>>>(ei1, fill1, col1);

    bf16 *hc[3] = { hbuf[0], hbuf[1], hbuf[2] };
    bf16 *hn[3] = { hbuf[3], hbuf[4], hbuf[5] };

    // single-step conv into slice 0 (decoder + fallback encoder)
    auto do_conv = [&](const float* xb, long long sB, long long sN) {
        gather_conv_k<<<dim3(10000, 1), 256, 0, stream>>>(
            xb, sB, sN, 0, rp0, col0, rp1, col1, Aconv);
        gemm_k<1, 1, 1, 0><<<dim3(2, 313, 1), 256, 0, stream>>>(
            Aconv, btconv, cbuf, bconv, 192, 256, 0, 0, 0);
    };
    // 40 sblk groups x 8 jblk x 8 strip-low = 2560 blocks (56 early-exit)
    auto do_grus = [&](const bf16* xin) {
        gru_fused_k<<<2560, 256, 0, stream>>>(
            xin, hc[0], hn[0], wpk[0], gbih[0], gbhh[0]);
        gru_fused_k<<<2560, 256, 0, stream>>>(
            hn[0], hc[1], hn[1], wpk[1], gbih[1], gbhh[1]);
        gru_fused_k<<<2560, 256, 0, stream>>>(
            hn[1], hc[2], hn[2], wpk[2], gbih[2], gbhh[2]);
        for (int g = 0; g < 3; ++g) { bf16* t = hc[g]; hc[g] = hn[g]; hn[g] = t; }
    };

    // encoder
    if (big) {
        // all 8 gathers in one launch (blockIdx.y = step), all 8 conv
        // GEMMs in one launch (blockIdx.z = step)
        gather_conv_k<<<dim3(10000, P_), 256, 0, stream>>>(
            x_seq, (long long)P_ * N_ * C_, C_, (long long)N_ * C_,
            rp0, col0, rp1, col1, Aconv);
        gemm_k<1, 1, 1, 0><<<dim3(2, 313, P_), 256, 0, stream>>>(
            Aconv, btconv, cbuf, bconv, 192, 256, 0,
            (size_t)MPAD * 192, (size_t)MPAD * 256);
        for (int ps = 0; ps < P_; ++ps)
            do_grus(cbuf + (size_t)ps * MPAD * 256);
    } else {
        for (int ps = 0; ps < P_; ++ps) {
            do_conv(x_seq + (size_t)ps * N_ * C_, (long long)P_ * N_ * C_, C_);
            do_grus(cbuf);
        }
    }

    // decoder: t=0 reuses encoder step-7 conv output (same x input).
    // In big mode that's cbuf slice 7; in fallback it's slice 0.
    const bf16* lastConv = big ? cbuf + (size_t)(P_ - 1) * MPAD * 256 : cbuf;
    float* out = (float*)d_out;
    for (int t = 0; t < HOR_; ++t) {
        if (t > 0) {
            do_conv(out + (size_t)(t - 1) * N_ * C_, (long long)HOR_ * N_ * C_, C_);
            lastConv = cbuf;
        }
        do_grus(lastConv);
        gemm_k<1, 0, 0, 1><<<dim3(1, 313, 1), 256, 0, stream>>>(
            hc[2], btproj, out, bproj, 256, 128, t, 0, 0);
    }
}

// Round 11
// 2638.313 us; speedup vs baseline: 1.0434x; 1.0050x over previous
//
#include <hip/hip_runtime.h>
#include <hip/hip_bf16.h>
#include <cstdint>

#define B_   4
#define P_   8
#define N_   10000
#define C_   64
#define H_   256
#define E_   160000
#define HOR_ 4
#define BN_  (B_ * N_)     // 40000
#define MPAD 40064         // 313 * 128

typedef __bf16 bf16;
typedef __attribute__((ext_vector_type(8))) __bf16 bf16x8;
typedef __attribute__((ext_vector_type(4))) float f32x4;

__device__ __forceinline__ void gl2lds16(const bf16* g, bf16* l) {
    __builtin_amdgcn_global_load_lds(
        (const __attribute__((address_space(1))) void*)g,
        (__attribute__((address_space(3))) void*)l, 16, 0, 0);
}

// ---------------------------------------------------------------- GEMM ----
// C[M,N] = A[M,K] @ Bt[N,K]^T. Round-0 proven structure (single-buffer,
// 2-barrier). Round-10 batching reverted: launch gaps were noise-level;
// batching mixed 8 x-slices in L2 for no gain.
template <int BIAS, int RELU, int OUTBF, int PROJ>
__global__ __launch_bounds__(256) void gemm_k(
    const bf16* __restrict__ A, const bf16* __restrict__ Bt,
    void* __restrict__ Cp, const float* __restrict__ bias,
    int K, int Nn, int tstep)
{
    __shared__ __align__(16) bf16 As[128 * 32];
    __shared__ __align__(16) bf16 Bs[128 * 32];

    const int tid  = threadIdx.x;
    const int m0   = blockIdx.y * 128;
    const int n0   = blockIdx.x * 128;
    const int wave = tid >> 6;
    const int lane = tid & 63;
    const int wm   = (wave >> 1) << 6;
    const int wn   = (wave & 1) << 6;
    const int lr   = lane & 15;
    const int kg   = lane >> 4;

    f32x4 acc[4][4] = {};

    const int r0 = tid >> 2;
    const int k0 = (tid & 3) << 3;

    for (int kk = 0; kk < K; kk += 32) {
        const bf16* ga = A  + (size_t)(m0 + r0) * K + kk + k0;
        const bf16* gb = Bt + (size_t)(n0 + r0) * K + kk + k0;
        gl2lds16(ga,                  As + tid * 8);
        gl2lds16(ga + 64 * (size_t)K, As + 2048 + tid * 8);
        gl2lds16(gb,                  Bs + tid * 8);
        gl2lds16(gb + 64 * (size_t)K, Bs + 2048 + tid * 8);
        __syncthreads();

        bf16x8 af[4], bfv[4];
#pragma unroll
        for (int i = 0; i < 4; ++i)
            af[i] = *reinterpret_cast<const bf16x8*>(&As[(wm + i * 16 + lr) * 32 + kg * 8]);
#pragma unroll
        for (int j = 0; j < 4; ++j)
            bfv[j] = *reinterpret_cast<const bf16x8*>(&Bs[(wn + j * 16 + lr) * 32 + kg * 8]);
#pragma unroll
        for (int i = 0; i < 4; ++i)
#pragma unroll
            for (int j = 0; j < 4; ++j)
                acc[i][j] = __builtin_amdgcn_mfma_f32_16x16x32_bf16(af[i], bfv[j], acc[i][j], 0, 0, 0);
        __syncthreads();
    }

#pragma unroll
    for (int i = 0; i < 4; ++i) {
#pragma unroll
        for (int j = 0; j < 4; ++j) {
#pragma unroll
            for (int v = 0; v < 4; ++v) {
                int row = m0 + wm + i * 16 + kg * 4 + v;
                int col = n0 + wn + j * 16 + lr;
                float val = acc[i][j][v];
                if (BIAS) val += bias[col];
                if (RELU) val = fmaxf(val, 0.f);
                if (PROJ) {
                    if (col < C_ && row < BN_) {
                        int b = row / N_, n = row - b * N_;
                        reinterpret_cast<float*>(Cp)[(((size_t)b * HOR_ + tstep) * N_ + n) * C_ + col] = val;
                    }
                } else if (OUTBF) {
                    reinterpret_cast<bf16*>(Cp)[(size_t)row * Nn + col] = (bf16)val;
                } else {
                    reinterpret_cast<float*>(Cp)[(size_t)row * Nn + col] = val;
                }
            }
        }
    }
}

// ----------------------------------------------------------- fused GRU ----
// EXACT round-5 config (session best): 128 rows x 32 gate-cols per block,
// XCD-aware swizzle, fused r/z acc (acc[4][4] = 64 AGPR), phase-split
// compute, W pre-packed fragment-major and loaded global->VGPR.
// Diagnosis (r3/r5/r8/r9 sweep): kernel sits at the per-CU operand-
// delivery wall (~8KB/wave-iter LDS-read + 6KB L1 W vs 116 matrix-cyc
// -> ~25% MfmaUtil cap; measured 22-23%). Occupancy 2x: null;
// scheduling variants: null/neg; (4,1) fragment geometry bytes/MFMA-
// optimal under the 64-AGPR accumulator floor. BANKED.
__global__ __launch_bounds__(256, 2) void gru_fused_k(
    const bf16* __restrict__ X, const bf16* __restrict__ Hc,
    bf16* __restrict__ Hn,
    const bf16* __restrict__ Wpk,
    const float* __restrict__ bih, const float* __restrict__ bhh)
{
    const int id    = blockIdx.x;
    const int sblk  = id >> 6;
    const int jblk  = (id >> 3) & 7;
    const int slow  = id & 7;
    const int strip = (sblk << 3) | slow;
    if (strip >= 313) return;

    __shared__ __align__(16) bf16 Xs[128 * 32];
    __shared__ __align__(16) bf16 Hs[128 * 32];

    const int tid  = threadIdx.x;
    const int m0   = strip * 128;
    const int j0   = jblk * 32;            // gate-col base (0..224)
    const int wave = tid >> 6;
    const int lane = tid & 63;
    const int wm   = (wave >> 1) << 6;     // 0 / 64
    const int wn   = (wave & 1) << 4;      // 0 / 16
    const int wv   = wave & 1;
    const int lr   = lane & 15;
    const int kg   = lane >> 4;

    f32x4 acc[4][4] = {};                  // [gate][i] : 64 AGPRs
                                           // 0=r 1=z 2=in(x) 3=hn(h)

    const int r0 = tid >> 2;
    const int k0 = (tid & 3) << 3;

    // packed-W per-thread base: fragment layout
    // [(jblk*2+wv)][it(8)][gate(6)][lane(64)][8 bf16]
    const bf16* wb = Wpk + (size_t)(jblk * 2 + wv) * 24576 + lane * 8;

    for (int it = 0; it < 8; ++it) {
        const int kk = it * 32;
        gl2lds16(X  + (size_t)(m0 + r0) * 256 + kk + k0,      Xs + tid * 8);
        gl2lds16(X  + (size_t)(m0 + r0 + 64) * 256 + kk + k0, Xs + 2048 + tid * 8);
        gl2lds16(Hc + (size_t)(m0 + r0) * 256 + kk + k0,      Hs + tid * 8);
        gl2lds16(Hc + (size_t)(m0 + r0 + 64) * 256 + kk + k0, Hs + 2048 + tid * 8);
        const bf16* wit = wb + it * 3072;
        bf16x8 w0 = *reinterpret_cast<const bf16x8*>(&wit[0]);
        bf16x8 w1 = *reinterpret_cast<const bf16x8*>(&wit[512]);
        bf16x8 w2 = *reinterpret_cast<const bf16x8*>(&wit[1024]);
        bf16x8 w3 = *reinterpret_cast<const bf16x8*>(&wit[1536]);
        bf16x8 w4 = *reinterpret_cast<const bf16x8*>(&wit[2048]);
        bf16x8 w5 = *reinterpret_cast<const bf16x8*>(&wit[2560]);
        __syncthreads();

        // phase A: X-side
        {
            bf16x8 fa[4];
#pragma unroll
            for (int i = 0; i < 4; ++i)
                fa[i] = *reinterpret_cast<const bf16x8*>(&Xs[(wm + i * 16 + lr) * 32 + kg * 8]);
#pragma unroll
            for (int i = 0; i < 4; ++i)
                acc[0][i] = __builtin_amdgcn_mfma_f32_16x16x32_bf16(fa[i], w0, acc[0][i], 0, 0, 0);
#pragma unroll
            for (int i = 0; i < 4; ++i)
                acc[1][i] = __builtin_amdgcn_mfma_f32_16x16x32_bf16(fa[i], w1, acc[1][i], 0, 0, 0);
#pragma unroll
            for (int i = 0; i < 4; ++i)
                acc[2][i] = __builtin_amdgcn_mfma_f32_16x16x32_bf16(fa[i], w2, acc[2][i], 0, 0, 0);
        }
        // phase B: H-side
        {
            bf16x8 fh[4];
#pragma unroll
            for (int i = 0; i < 4; ++i)
                fh[i] = *reinterpret_cast<const bf16x8*>(&Hs[(wm + i * 16 + lr) * 32 + kg * 8]);
#pragma unroll
            for (int i = 0; i < 4; ++i)
                acc[0][i] = __builtin_amdgcn_mfma_f32_16x16x32_bf16(fh[i], w3, acc[0][i], 0, 0, 0);
#pragma unroll
            for (int i = 0; i < 4; ++i)
                acc[1][i] = __builtin_amdgcn_mfma_f32_16x16x32_bf16(fh[i], w4, acc[1][i], 0, 0, 0);
#pragma unroll
            for (int i = 0; i < 4; ++i)
                acc[3][i] = __builtin_amdgcn_mfma_f32_16x16x32_bf16(fh[i], w5, acc[3][i], 0, 0, 0);
        }
        __syncthreads();
    }

    const int col = j0 + wn + lr;
    const float b_r  = bih[col]       + bhh[col];
    const float b_z  = bih[256 + col] + bhh[256 + col];
    const float bi_n = bih[512 + col];
    const float bh_n = bhh[512 + col];
#pragma unroll
    for (int i = 0; i < 4; ++i) {
#pragma unroll
        for (int v = 0; v < 4; ++v) {
            int row = m0 + wm + i * 16 + kg * 4 + v;
            float r = __fdividef(1.f, 1.f + __expf(-(acc[0][i][v] + b_r)));
            float z = __fdividef(1.f, 1.f + __expf(-(acc[1][i][v] + b_z)));
            float a = (acc[2][i][v] + bi_n) + r * (acc[3][i][v] + bh_n);
            a = fminf(fmaxf(a, -15.f), 15.f);
            float t2 = __expf(2.f * a);
            float nn = __fdividef(t2 - 1.f, t2 + 1.f);
            float hold = (float)Hc[(size_t)row * 256 + col];
            Hn[(size_t)row * 256 + col] = (bf16)((1.f - z) * nn + z * hold);
        }
    }
}

// ----------------------------------------------------- x -> bf16 staging ----
// Round-11: gather traffic is Sigma(deg) x rowbytes, L3-resident (~327MB
// f32 per conv step, ~30us x 12 = dominant non-GRU cost). A-entries are
// cast to bf16 anyway, so pre-round x to bf16 once (15MB traffic, ~3us)
// and gather 128B rows instead of 256B: gather traffic halved.
struct __attribute__((aligned(8))) bf4 { bf16 b[4]; };

__global__ __launch_bounds__(256) void cvt_x_k(
    const float* __restrict__ xbase, long long sB, long long sN,
    bf16* __restrict__ xbf)
{
    int i4 = blockIdx.x * 256 + threadIdx.x;      // one float4 per thread
    if (i4 >= BN_ * 16) return;
    int row = i4 >> 4;
    int b   = row / N_;
    int n   = row - b * N_;
    int c   = (i4 & 15) << 2;
    const float4 v = *reinterpret_cast<const float4*>(
        &xbase[(size_t)b * sB + (size_t)n * sN + c]);
    bf4 o;
    o.b[0] = (bf16)v.x; o.b[1] = (bf16)v.y; o.b[2] = (bf16)v.z; o.b[3] = (bf16)v.w;
    *reinterpret_cast<bf4*>(&xbf[(size_t)row * 64 + c]) = o;
}

// ------------------------------------------------- conv A-matrix build ----
// Reads pre-converted bf16 x rows (128B instead of 256B per edge).
__global__ __launch_bounds__(256) void gather_conv_k(
    const bf16* __restrict__ xbf,
    const int* __restrict__ rp0, const int* __restrict__ col0,
    const int* __restrict__ rp1, const int* __restrict__ col1,
    bf16* __restrict__ Aconv)
{
    int wid  = (blockIdx.x * 256 + threadIdx.x) >> 6;
    int lane = threadIdx.x & 63;
    if (wid >= BN_) return;
    int b = wid / N_;
    int n = wid - b * N_;
    int eg = lane >> 4;
    int cl = lane & 15;
    const bf16* xb = xbf + (size_t)b * N_ * 64;

    bf4 xv = *reinterpret_cast<const bf4*>(&xb[(size_t)n * 64 + cl * 4]);

    float4 s0 = {0.f, 0.f, 0.f, 0.f};
    int st = rp0[n], en = rp0[n + 1];
    float d0 = fmaxf((float)(en - st), 1.f);
    for (int e = st + eg; e < en; e += 4) {
        const bf4 v = *reinterpret_cast<const bf4*>(&xb[(size_t)col0[e] * 64 + cl * 4]);
        s0.x += (float)v.b[0]; s0.y += (float)v.b[1];
        s0.z += (float)v.b[2]; s0.w += (float)v.b[3];
    }

    float4 s1 = {0.f, 0.f, 0.f, 0.f};
    st = rp1[n]; en = rp1[n + 1];
    float d1 = fmaxf((float)(en - st), 1.f);
    for (int e = st + eg; e < en; e += 4) {
        const bf4 v = *reinterpret_cast<const bf4*>(&xb[(size_t)col1[e] * 64 + cl * 4]);
        s1.x += (float)v.b[0]; s1.y += (float)v.b[1];
        s1.z += (float)v.b[2]; s1.w += (float)v.b[3];
    }

#pragma unroll
    for (int m = 16; m <= 32; m <<= 1) {
        s0.x += __shfl_xor(s0.x, m, 64); s0.y += __shfl_xor(s0.y, m, 64);
        s0.z += __shfl_xor(s0.z, m, 64); s0.w += __shfl_xor(s0.w, m, 64);
        s1.x += __shfl_xor(s1.x, m, 64); s1.y += __shfl_xor(s1.y, m, 64);
        s1.z += __shfl_xor(s1.z, m, 64); s1.w += __shfl_xor(s1.w, m, 64);
    }

    if (eg == 0) {
        float r0 = 1.f / d0, r1 = 1.f / d1;
        bf16* row = Aconv + (size_t)wid * 192;
        bf4 o;
        o.b[0] = (bf16)(s0.x * r0); o.b[1] = (bf16)(s0.y * r0);
        o.b[2] = (bf16)(s0.z * r0); o.b[3] = (bf16)(s0.w * r0);
        *reinterpret_cast<bf4*>(&row[cl * 4]) = o;
        *reinterpret_cast<bf4*>(&row[64 + cl * 4]) = xv;
        o.b[0] = (bf16)(s1.x * r1); o.b[1] = (bf16)(s1.y * r1);
        o.b[2] = (bf16)(s1.z * r1); o.b[3] = (bf16)(s1.w * r1);
        *reinterpret_cast<bf4*>(&row[128 + cl * 4]) = o;
    }
}

// ------------------------------------------------------------ CSR build ----
__global__ void count_k(const int* __restrict__ ei, int* __restrict__ cnt) {
    int e = blockIdx.x * 256 + threadIdx.x;
    if (e < E_) atomicAdd(&cnt[ei[E_ + e]], 1);
}

__global__ __launch_bounds__(1024) void scan_k(
    const int* __restrict__ cnt, int* __restrict__ rp, int* __restrict__ fill)
{
    __shared__ int sums[1024];
    int t = threadIdx.x;
    const int chunk = 10;
    int lo = t * chunk;
    int hi = lo + chunk; if (hi > N_) hi = N_;
    int s = 0;
    for (int i = lo; i < hi; ++i) s += cnt[i];
    sums[t] = s;
    __syncthreads();
    for (int off = 1; off < 1024; off <<= 1) {
        int u = (t >= off) ? sums[t - off] : 0;
        __syncthreads();
        sums[t] += u;
        __syncthreads();
    }
    int base = (t == 0) ? 0 : sums[t - 1];
    for (int i = lo; i < hi; ++i) { rp[i] = base; fill[i] = base; base += cnt[i]; }
    if (t == 1023) rp[N_] = sums[1023];
}

__global__ void fill_k(const int* __restrict__ ei, int* __restrict__ fill,
                       int* __restrict__ colarr) {
    int e = blockIdx.x * 256 + threadIdx.x;
    if (e < E_) {
        int p = atomicAdd(&fill[ei[E_ + e]], 1);
        colarr[p] = ei[e];
    }
}

// --------------------------------------------------------- weight prep ----
// Pack GRU weights fragment-major so a wave's MFMA B-fragment is one
// contiguous 1024B line: out[(jb*2+wv)][it][g][lane][e] =
// W6[g][jb*32+wv*16+(lane&15)][it*32+(lane>>4)*8+e], W6 = Wih(g<3)/Whh.
__global__ void pack_w_k(const float* __restrict__ Wih, const float* __restrict__ Whh,
                         bf16* __restrict__ out) {
    int idx = blockIdx.x * 256 + threadIdx.x;
    if (idx >= 6 * 256 * 256) return;
    int e    = idx & 7;
    int lane = (idx >> 3) & 63;
    int rest = idx >> 9;
    int g    = rest % 6;
    int it   = (rest / 6) & 7;
    int wj   = rest / 48;             // jb*2 + wv
    int row  = (wj >> 1) * 32 + (wj & 1) * 16 + (lane & 15);
    int k    = it * 32 + (lane >> 4) * 8 + e;
    float v  = (g < 3) ? Wih[(g * 256 + row) * 256 + k]
                       : Whh[((g - 3) * 256 + row) * 256 + k];
    out[idx] = (bf16)v;
}

__global__ void build_conv_bt_k(const float* __restrict__ Wl0, const float* __restrict__ Wr0,
                                const float* __restrict__ Wl1, const float* __restrict__ Wr1,
                                bf16* __restrict__ Bt) {
    int idx = blockIdx.x * 256 + threadIdx.x;
    if (idx >= 256 * 192) return;
    int n = idx / 192, k = idx - n * 192;
    float v;
    if (k < 64)       v = Wl0[k * 256 + n];
    else if (k < 128) v = Wr0[(k - 64) * 256 + n] + Wr1[(k - 64) * 256 + n];
    else              v = Wl1[(k - 128) * 256 + n];
    Bt[idx] = (bf16)v;
}

__global__ void build_conv_bias_k(const float* __restrict__ bl0, const float* __restrict__ bl1,
                                  float* __restrict__ bias) {
    int i = threadIdx.x;
    if (i < 256) bias[i] = bl0[i] + bl1[i];
}

__global__ void build_proj_k(const float* __restrict__ Wp, const float* __restrict__ bp,
                             bf16* __restrict__ Bt, float* __restrict__ bias) {
    int idx = blockIdx.x * 256 + threadIdx.x;
    if (idx < 128 * 256) {
        int n = idx >> 8, k = idx & 255;
        Bt[idx] = (bf16)(n < 64 ? Wp[n * 256 + k] : 0.f);
    }
    if (idx < 128) bias[idx] = (idx < 64) ? bp[idx] : 0.f;
}

// ---------------------------------------------------------------- host ----
extern "C" void kernel_launch(void* const* d_in, const int* in_sizes, int n_in,
                              void* d_out, int out_size, void* d_ws, size_t ws_size,
                              hipStream_t stream)
{
    const float* x_seq = (const float*)d_in[0];
    const int*   ei0   = (const int*)d_in[1];
    const int*   ei1   = (const int*)d_in[2];
    const float* Wl0   = (const float*)d_in[3];
    const float* bl0   = (const float*)d_in[4];
    const float* Wr0   = (const float*)d_in[5];
    const float* Wl1   = (const float*)d_in[6];
    const float* bl1   = (const float*)d_in[7];
    const float* Wr1   = (const float*)d_in[8];
    const float* Wp    = (const float*)d_in[9];
    const float* bp    = (const float*)d_in[10];
    const float* gWih[3], *gWhh[3], *gbih[3], *gbhh[3];
    for (int g = 0; g < 3; ++g) {
        gWih[g] = (const float*)d_in[11 + 4 * g];
        gWhh[g] = (const float*)d_in[12 + 4 * g];
        gbih[g] = (const float*)d_in[13 + 4 * g];
        gbhh[g] = (const float*)d_in[14 + 4 * g];
    }

    char* p = (char*)d_ws;
    auto alloc = [&](size_t bytes) -> char* {
        char* r = p; p += (bytes + 255) & ~(size_t)255; return r;
    };
    bf16*  Aconv  = (bf16*)alloc((size_t)MPAD * 192 * 2);
    bf16*  cbuf   = (bf16*)alloc((size_t)MPAD * 256 * 2);
    bf16*  xbf    = (bf16*)alloc((size_t)BN_ * 64 * 2);
    bf16*  hbuf[6];
    for (int g = 0; g < 6; ++g) hbuf[g] = (bf16*)alloc((size_t)MPAD * 256 * 2);
    bf16*  wpk[3];
    for (int g = 0; g < 3; ++g)
        wpk[g] = (bf16*)alloc((size_t)6 * 256 * 256 * 2);
    bf16*  btconv = (bf16*)alloc((size_t)256 * 192 * 2);
    float* bconv  = (float*)alloc(256 * 4);
    bf16*  btproj = (bf16*)alloc((size_t)128 * 256 * 2);
    float* bproj  = (float*)alloc(128 * 4);
    int* cnt0  = (int*)alloc(N_ * 4);
    int* cnt1  = (int*)alloc(N_ * 4);
    int* rp0   = (int*)alloc((N_ + 1) * 4);
    int* rp1   = (int*)alloc((N_ + 1) * 4);
    int* fill0 = (int*)alloc((N_ + 1) * 4);
    int* fill1 = (int*)alloc((N_ + 1) * 4);
    int* col0  = (int*)alloc(E_ * 4);
    int* col1  = (int*)alloc(E_ * 4);

    // h cur buffers (0,1,2) must start at zero; nxt (3,4,5) fully written.
    hipMemsetAsync(Aconv, 0, (size_t)MPAD * 192 * 2, stream);
    for (int g = 0; g < 3; ++g)
        hipMemsetAsync(hbuf[g], 0, (size_t)MPAD * 256 * 2, stream);
    hipMemsetAsync(cnt0, 0, N_ * 4, stream);
    hipMemsetAsync(cnt1, 0, N_ * 4, stream);

    for (int g = 0; g < 3; ++g)
        pack_w_k<<<1536, 256, 0, stream>>>(gWih[g], gWhh[g], wpk[g]);
    build_conv_bt_k<<<192, 256, 0, stream>>>(Wl0, Wr0, Wl1, Wr1, btconv);
    build_conv_bias_k<<<1, 256, 0, stream>>>(bl0, bl1, bconv);
    build_proj_k<<<128, 256, 0, stream>>>(Wp, bp, btproj, bproj);

    count_k<<<(E_ + 255) / 256, 256, 0, stream>>>(ei0, cnt0);
    count_k<<<(E_ + 255) / 256, 256, 0, stream>>>(ei1, cnt1);
    scan_k<<<1, 1024, 0, stream>>>(cnt0, rp0, fill0);
    scan_k<<<1, 1024, 0, stream>>>(cnt1, rp1, fill1);
    fill_k<<<(E_ + 255) / 256, 256, 0, stream>>>(ei0, fill0, col0);
    fill_k<<<(E_ + 255) / 256, 256, 0, stream>>>(ei1, fill1, col1);

    bf16 *hc[3] = { hbuf[0], hbuf[1], hbuf[2] };
    bf16 *hn[3] = { hbuf[3], hbuf[4], hbuf[5] };

    auto do_conv = [&](const float* xb, long long sB, long long sN) {
        cvt_x_k<<<(BN_ * 16 + 255) / 256, 256, 0, stream>>>(xb, sB, sN, xbf);
        gather_conv_k<<<10000, 256, 0, stream>>>(xbf, rp0, col0, rp1, col1, Aconv);
        gemm_k<1, 1, 1, 0><<<dim3(2, 313, 1), 256, 0, stream>>>(
            Aconv, btconv, cbuf, bconv, 192, 256, 0);
    };
    // 40 sblk groups x 8 jblk x 8 strip-low = 2560 blocks (56 early-exit)
    auto do_grus = [&]() {
        gru_fused_k<<<2560, 256, 0, stream>>>(
            cbuf, hc[0], hn[0], wpk[0], gbih[0], gbhh[0]);
        gru_fused_k<<<2560, 256, 0, stream>>>(
            hn[0], hc[1], hn[1], wpk[1], gbih[1], gbhh[1]);
        gru_fused_k<<<2560, 256, 0, stream>>>(
            hn[1], hc[2], hn[2], wpk[2], gbih[2], gbhh[2]);
        for (int g = 0; g < 3; ++g) { bf16* t = hc[g]; hc[g] = hn[g]; hn[g] = t; }
    };

    // encoder
    for (int ps = 0; ps < P_; ++ps) {
        do_conv(x_seq + (size_t)ps * N_ * C_, (long long)P_ * N_ * C_, C_);
        do_grus();
    }

    // decoder: t=0 reuses encoder step-7 conv output (same x input)
    float* out = (float*)d_out;
    for (int t = 0; t < HOR_; ++t) {
        if (t > 0)
            do_conv(out + (size_t)(t - 1) * N_ * C_, (long long)HOR_ * N_ * C_, C_);
        do_grus();
        gemm_k<1, 0, 0, 1><<<dim3(1, 313, 1), 256, 0, stream>>>(
            hc[2], btproj, out, bproj, 256, 128, t);
    }
}